// Round 1
// baseline (882.108 us; speedup 1.0000x reference)
//
#include <hip/hip_runtime.h>
#include <hip/hip_bf16.h>

typedef unsigned int uint32;
typedef unsigned short ushort16;

#define N_ 64
#define C_ 1024
#define Q_ 128
#define F_ 512

__device__ __forceinline__ ushort16 f2bf(float x) {
    uint32 b = __float_as_uint(x);
    uint32 r = (b + 0x7FFFu + ((b >> 16) & 1u)) >> 16;
    return (ushort16)r;
}
__device__ __forceinline__ float bf2f_lo(uint32 p) { return __uint_as_float(p << 16); }
__device__ __forceinline__ float bf2f_hi(uint32 p) { return __uint_as_float(p & 0xFFFF0000u); }

// ---------------- K0: s_qry[n][q] = dot(x_query[n][q][:], w_context) ----------------
__global__ void k0_sqry(const float* __restrict__ xq, const float* __restrict__ wctx,
                        float* __restrict__ s_qry) {
    int wave = (int)((blockIdx.x * blockDim.x + threadIdx.x) >> 6);
    int lane = threadIdx.x & 63;
    if (wave >= N_ * Q_) return;
    const float* row = xq + (size_t)wave * F_;
    float acc = 0.f;
#pragma unroll
    for (int r = 0; r < 2; ++r) {
        float4 v = *(const float4*)(row + lane * 8 + r * 4);
        float4 w = *(const float4*)(wctx + lane * 8 + r * 4);
        acc += v.x * w.x + v.y * w.y + v.z * w.z + v.w * w.w;
    }
#pragma unroll
    for (int off = 32; off >= 1; off >>= 1) acc += __shfl_xor(acc, off, 64);
    if (lane == 0) s_qry[wave] = acc;
}

// ---------------- K1: main fused kernel, one block per (n, 128-row c-tile) ----------
__launch_bounds__(256, 2)
__global__ void k1_main(const float* __restrict__ xc, const float* __restrict__ xq,
                        const float* __restrict__ wctx, const float* __restrict__ wcq,
                        const float* __restrict__ s_qry,
                        float* __restrict__ out, float* __restrict__ ws_part) {
    __shared__ __align__(16) unsigned char arena[64 * 1024];
    float* smA = (float*)arena;                       // [32f][128c] phase A
    float* smB = (float*)(arena + 16 * 1024);         // [32f][128q] phase A
    ushort16* smW = (ushort16*)arena;                 // [128q][128c] bf16 (aliases A/B)
    ushort16* smX = (ushort16*)(arena + 32 * 1024);   // [128q][128f] bf16 per f-chunk

    __shared__ float s_wcq[512], s_wct[512];
    __shared__ float s_sctx[128], s_rowmax[128], s_ew[128];
    __shared__ float s_red[8];
    __shared__ float s_P[512];

    const int tid = threadIdx.x;
    const int tx = tid & 15, ty = tid >> 4;
    const int n = blockIdx.y, cb = blockIdx.x;
    const int c0 = cb * 128;
    const float* xcn = xc + ((size_t)n * C_ + c0) * F_;   // [128][512] tile
    const float* xqn = xq + (size_t)n * Q_ * F_;          // [128][512]

    for (int k = tid; k < 512; k += 256) {
        s_wcq[k] = wcq[k];
        s_wct[k] = wctx[k];
        s_P[k] = 0.f;
    }

    float acc[8][8];
#pragma unroll
    for (int i = 0; i < 8; ++i)
#pragma unroll
        for (int j = 0; j < 8; ++j) acc[i][j] = 0.f;
    float scp[4] = {0.f, 0.f, 0.f, 0.f};

    const int cl = tid >> 3;          // 0..31
    const int fl = (tid & 7) * 4;     // 0,4,..28

    __syncthreads();

    // ---------- Phase A: sim = (xc*wcq) @ xq^T in fp32 ----------
    for (int f0 = 0; f0 < 512; f0 += 32) {
        __syncthreads();
#pragma unroll
        for (int rep = 0; rep < 4; ++rep) {
            int c = cl + rep * 32;
            float4 v = *(const float4*)(xcn + (size_t)c * F_ + f0 + fl);
            scp[rep] += v.x * s_wct[f0 + fl] + v.y * s_wct[f0 + fl + 1] +
                        v.z * s_wct[f0 + fl + 2] + v.w * s_wct[f0 + fl + 3];
            smA[(fl + 0) * 128 + c] = v.x * s_wcq[f0 + fl + 0];
            smA[(fl + 1) * 128 + c] = v.y * s_wcq[f0 + fl + 1];
            smA[(fl + 2) * 128 + c] = v.z * s_wcq[f0 + fl + 2];
            smA[(fl + 3) * 128 + c] = v.w * s_wcq[f0 + fl + 3];
            int q = cl + rep * 32;
            float4 u = *(const float4*)(xqn + (size_t)q * F_ + f0 + fl);
            smB[(fl + 0) * 128 + q] = u.x;
            smB[(fl + 1) * 128 + q] = u.y;
            smB[(fl + 2) * 128 + q] = u.z;
            smB[(fl + 3) * 128 + q] = u.w;
        }
        __syncthreads();
#pragma unroll 8
        for (int fi = 0; fi < 32; ++fi) {
            float4 a0 = *(const float4*)&smA[fi * 128 + ty * 8];
            float4 a1 = *(const float4*)&smA[fi * 128 + ty * 8 + 4];
            float4 b0 = *(const float4*)&smB[fi * 128 + tx * 8];
            float4 b1 = *(const float4*)&smB[fi * 128 + tx * 8 + 4];
            float av[8] = {a0.x, a0.y, a0.z, a0.w, a1.x, a1.y, a1.z, a1.w};
            float bv[8] = {b0.x, b0.y, b0.z, b0.w, b1.x, b1.y, b1.z, b1.w};
#pragma unroll
            for (int i = 0; i < 8; ++i)
#pragma unroll
                for (int j = 0; j < 8; ++j) acc[i][j] = fmaf(av[i], bv[j], acc[i][j]);
        }
    }

    // s_ctx reduce (8 threads per c, consecutive lanes)
#pragma unroll
    for (int rep = 0; rep < 4; ++rep) {
        float v = scp[rep];
        v += __shfl_xor(v, 1, 64);
        v += __shfl_xor(v, 2, 64);
        v += __shfl_xor(v, 4, 64);
        if ((tid & 7) == 0) s_sctx[cl + rep * 32] = v;
    }
    __syncthreads();   // also guarantees GEMM1 LDS reads complete before W overwrite

    // ---------- softmax over q (per row), all in registers ----------
    float sq[8];
    {
        float4 q0 = *(const float4*)(s_qry + n * Q_ + tx * 8);
        float4 q1 = *(const float4*)(s_qry + n * Q_ + tx * 8 + 4);
        sq[0] = q0.x; sq[1] = q0.y; sq[2] = q0.z; sq[3] = q0.w;
        sq[4] = q1.x; sq[5] = q1.y; sq[6] = q1.z; sq[7] = q1.w;
    }
    float rowinv[8], rmax[8];
#pragma unroll
    for (int i = 0; i < 8; ++i) {
        float sc = s_sctx[ty * 8 + i];
        float m = -1e30f;
#pragma unroll
        for (int j = 0; j < 8; ++j) {
            acc[i][j] += sc + sq[j];
            m = fmaxf(m, acc[i][j]);
        }
        m = fmaxf(m, __shfl_xor(m, 1, 64));
        m = fmaxf(m, __shfl_xor(m, 2, 64));
        m = fmaxf(m, __shfl_xor(m, 4, 64));
        m = fmaxf(m, __shfl_xor(m, 8, 64));
        float s = 0.f;
#pragma unroll
        for (int j = 0; j < 8; ++j) {
            acc[i][j] = __expf(acc[i][j] - m);
            s += acc[i][j];
        }
        s += __shfl_xor(s, 1, 64);
        s += __shfl_xor(s, 2, 64);
        s += __shfl_xor(s, 4, 64);
        s += __shfl_xor(s, 8, 64);
        rmax[i] = m;
        rowinv[i] = 1.0f / s;
    }

    // write W^T (q-major, bf16) into arena (GEMM1 buffers dead)
#pragma unroll
    for (int j = 0; j < 8; ++j) {
        int q = tx * 8 + j;
        uint4 u;
        u.x = (uint32)f2bf(acc[0][j]) | ((uint32)f2bf(acc[1][j]) << 16);
        u.y = (uint32)f2bf(acc[2][j]) | ((uint32)f2bf(acc[3][j]) << 16);
        u.z = (uint32)f2bf(acc[4][j]) | ((uint32)f2bf(acc[5][j]) << 16);
        u.w = (uint32)f2bf(acc[6][j]) | ((uint32)f2bf(acc[7][j]) << 16);
        *(uint4*)&smW[q * 128 + ty * 8] = u;
    }
    if (tx == 0) {
#pragma unroll
        for (int i = 0; i < 8; ++i) s_rowmax[ty * 8 + i] = rmax[i];
    }
    __syncthreads();

    // ---------- block-level q2c prep: Mb, ew, Lb ----------
    {
        float v = (tid < 128) ? s_rowmax[tid] : -1e30f;
#pragma unroll
        for (int off = 1; off <= 32; off <<= 1) v = fmaxf(v, __shfl_xor(v, off, 64));
        if ((tid & 63) == 0) s_red[tid >> 6] = v;
    }
    __syncthreads();
    float Mb = fmaxf(fmaxf(s_red[0], s_red[1]), fmaxf(s_red[2], s_red[3]));
    float ewv = (tid < 128) ? __expf(s_rowmax[tid] - Mb) : 0.f;
    if (tid < 128) s_ew[tid] = ewv;
    {
        float w = ewv;
#pragma unroll
        for (int off = 1; off <= 32; off <<= 1) w += __shfl_xor(w, off, 64);
        if ((tid & 63) == 0) s_red[4 + (tid >> 6)] = w;
    }
    __syncthreads();
    if (tid == 0) {
        float Lb = s_red[4] + s_red[5] + s_red[6] + s_red[7];
        size_t off = ((size_t)(n * 8 + cb)) * 514;
        ws_part[off + 512] = Mb;
        ws_part[off + 513] = Lb;
    }
    float rew[8];
#pragma unroll
    for (int i = 0; i < 8; ++i) rew[i] = s_ew[ty * 8 + i];

    // ---------- Phase B/C: x_c2q = W @ xq (bf16 operands), fused epilogue ----------
    for (int fc = 0; fc < 4; ++fc) {
        __syncthreads();
        {   // stage xq chunk [128q][128f] as bf16
            int q = tid >> 1;
            int fh = (tid & 1) * 64;
            const float* src = xqn + (size_t)q * F_ + fc * 128 + fh;
#pragma unroll
            for (int k = 0; k < 8; ++k) {
                float4 v0 = *(const float4*)(src + k * 8);
                float4 v1 = *(const float4*)(src + k * 8 + 4);
                uint4 o;
                o.x = (uint32)f2bf(v0.x) | ((uint32)f2bf(v0.y) << 16);
                o.y = (uint32)f2bf(v0.z) | ((uint32)f2bf(v0.w) << 16);
                o.z = (uint32)f2bf(v1.x) | ((uint32)f2bf(v1.y) << 16);
                o.w = (uint32)f2bf(v1.z) | ((uint32)f2bf(v1.w) << 16);
                *(uint4*)&smX[(size_t)q * 128 + fh + k * 8] = o;
            }
        }
        __syncthreads();

        float acc2[8][8];
#pragma unroll
        for (int i = 0; i < 8; ++i)
#pragma unroll
            for (int j = 0; j < 8; ++j) acc2[i][j] = 0.f;

#pragma unroll 2
        for (int q = 0; q < 128; ++q) {
            uint4 wr = *(const uint4*)&smW[q * 128 + ty * 8];
            uint4 xr = *(const uint4*)&smX[q * 128 + tx * 8];
            float wv[8] = {bf2f_lo(wr.x), bf2f_hi(wr.x), bf2f_lo(wr.y), bf2f_hi(wr.y),
                           bf2f_lo(wr.z), bf2f_hi(wr.z), bf2f_lo(wr.w), bf2f_hi(wr.w)};
            float xv[8] = {bf2f_lo(xr.x), bf2f_hi(xr.x), bf2f_lo(xr.y), bf2f_hi(xr.y),
                           bf2f_lo(xr.z), bf2f_hi(xr.z), bf2f_lo(xr.w), bf2f_hi(xr.w)};
#pragma unroll
            for (int i = 0; i < 8; ++i)
#pragma unroll
                for (int j = 0; j < 8; ++j) acc2[i][j] = fmaf(wv[i], xv[j], acc2[i][j]);
        }

        // epilogue: write out sections 0,1,2 + accumulate q2c partial P
        float pp[8] = {0.f, 0.f, 0.f, 0.f, 0.f, 0.f, 0.f, 0.f};
#pragma unroll
        for (int i = 0; i < 8; ++i) {
            int c = ty * 8 + i;
            const float* xrow = xcn + (size_t)c * F_ + fc * 128 + tx * 8;
            float4 x0 = *(const float4*)(xrow);
            float4 x1 = *(const float4*)(xrow + 4);
            float inv = rowinv[i];
            float4 c2q0 = make_float4(acc2[i][0] * inv, acc2[i][1] * inv,
                                      acc2[i][2] * inv, acc2[i][3] * inv);
            float4 c2q1 = make_float4(acc2[i][4] * inv, acc2[i][5] * inv,
                                      acc2[i][6] * inv, acc2[i][7] * inv);
            float* orow = out + ((size_t)n * C_ + c0 + c) * 2048 + fc * 128 + tx * 8;
            *(float4*)(orow) = x0;
            *(float4*)(orow + 4) = x1;
            *(float4*)(orow + 512) = c2q0;
            *(float4*)(orow + 516) = c2q1;
            *(float4*)(orow + 1024) = make_float4(x0.x * c2q0.x, x0.y * c2q0.y,
                                                  x0.z * c2q0.z, x0.w * c2q0.w);
            *(float4*)(orow + 1028) = make_float4(x1.x * c2q1.x, x1.y * c2q1.y,
                                                  x1.z * c2q1.z, x1.w * c2q1.w);
            float e = rew[i];
            pp[0] = fmaf(e, x0.x, pp[0]); pp[1] = fmaf(e, x0.y, pp[1]);
            pp[2] = fmaf(e, x0.z, pp[2]); pp[3] = fmaf(e, x0.w, pp[3]);
            pp[4] = fmaf(e, x1.x, pp[4]); pp[5] = fmaf(e, x1.y, pp[5]);
            pp[6] = fmaf(e, x1.z, pp[6]); pp[7] = fmaf(e, x1.w, pp[7]);
        }
#pragma unroll
        for (int j = 0; j < 8; ++j) atomicAdd(&s_P[fc * 128 + tx * 8 + j], pp[j]);
    }
    __syncthreads();
    {
        size_t off = ((size_t)(n * 8 + cb)) * 514;
        for (int k = tid; k < 512; k += 256) ws_part[off + k] = s_P[k];
    }
}

// ---------------- K2: combine q2c partials -> x_q2c[n][512] ----------------
__global__ void k2_combine(const float* __restrict__ ws_part, float* __restrict__ xq2c) {
    int n = blockIdx.x;
    int tid = threadIdx.x;
    const float* base = ws_part + (size_t)n * 8 * 514;
    float M = -1e30f;
#pragma unroll
    for (int b = 0; b < 8; ++b) M = fmaxf(M, base[b * 514 + 512]);
    float denom = 0.f;
#pragma unroll
    for (int b = 0; b < 8; ++b) denom += base[b * 514 + 513] * __expf(base[b * 514 + 512] - M);
    float inv = 1.0f / denom;
    for (int f = tid; f < 512; f += 256) {
        float a = 0.f;
#pragma unroll
        for (int b = 0; b < 8; ++b) a += base[b * 514 + f] * __expf(base[b * 514 + 512] - M);
        xq2c[n * 512 + f] = a * inv;
    }
}

// ---------------- K3: out section 3 = x_ctx * x_q2c (broadcast) ----------------
__global__ void k3_out3(const float* __restrict__ xc, const float* __restrict__ xq2c,
                        float* __restrict__ out) {
    const size_t total4 = (size_t)N_ * C_ * F_ / 4;   // 8,388,608 float4s
    size_t stride = (size_t)gridDim.x * blockDim.x;
    for (size_t idx = (size_t)blockIdx.x * blockDim.x + threadIdx.x; idx < total4; idx += stride) {
        size_t nn = idx >> 17;          // / (C*F/4 = 131072)
        size_t r = idx & 131071;
        size_t c = r >> 7;              // / (F/4 = 128)
        size_t f4 = r & 127;
        float4 x = ((const float4*)xc)[idx];
        float4 g = ((const float4*)xq2c)[nn * 128 + f4];
        float4 o = make_float4(x.x * g.x, x.y * g.y, x.z * g.z, x.w * g.w);
        ((float4*)(out + (nn * C_ + c) * 2048 + 1536))[f4] = o;
    }
}

extern "C" void kernel_launch(void* const* d_in, const int* in_sizes, int n_in,
                              void* d_out, int out_size, void* d_ws, size_t ws_size,
                              hipStream_t stream) {
    const float* xc = (const float*)d_in[0];    // x_context [64][1024][512]
    const float* xq = (const float*)d_in[1];    // x_query   [64][128][512]
    const float* wctx = (const float*)d_in[2];  // w_context [512]
    // d_in[3] = w_query (unused by reference)
    const float* wcq = (const float*)d_in[4];   // w_cq      [512]
    float* out = (float*)d_out;
    float* ws = (float*)d_ws;

    float* s_qry = ws;                      // 8192 floats
    float* part = ws + 8192;                // 64*8*514 = 263168 floats
    float* xq2c = ws + 8192 + 263168;       // 64*512 = 32768 floats

    k0_sqry<<<2048, 256, 0, stream>>>(xq, wctx, s_qry);
    dim3 g1(8, 64);
    k1_main<<<g1, 256, 0, stream>>>(xc, xq, wctx, wcq, s_qry, out, part);
    k2_combine<<<64, 256, 0, stream>>>(part, xq2c);
    k3_out3<<<4096, 256, 0, stream>>>(xc, xq2c, out);
}